// Round 7
// baseline (683.207 us; speedup 1.0000x reference)
//
#include <hip/hip_runtime.h>
#include <cstdint>
#include <cstddef>

#define NPIX 9216          // 96*96
#define NB 2
#define NC 256
#define RC 64
#define TK 16
#define NROWS (NB * NPIX)  // 18432
#define NQ 9               // col splits
#define QC 1024            // cols per split
#define CT 128             // cols per LDS tile
#define NT2 8              // tiles per split
#define SST 72             // LDS col stride in ushorts
#define NCHK 576           // 16-col subtile maxima per row
#define MAXS 48            // candidate subtile cap per row
#define MAXG 12            // score groups (4 subtiles each)
#define MARGIN 0.0082f     // 2*e, e <= (2*2^-9 + 2^-18) * ||a||*||b||

typedef unsigned short ushort_t;
typedef unsigned int uint_t;
typedef __bf16 bf16x8 __attribute__((ext_vector_type(8)));
typedef float f32x4 __attribute__((ext_vector_type(4)));

__device__ __forceinline__ uint_t f2bf(float x) {
  uint_t u = __float_as_uint(x);
  return (u + 0x7FFFu + ((u >> 16) & 1u)) >> 16;
}

// monotone float->uint map (bigger float => bigger uint)
__device__ __forceinline__ uint_t ordu(float v) {
  uint_t u = __float_as_uint(v);
  return (u & 0x80000000u) ? ~u : (u | 0x80000000u);
}
// inverse of ordu
__device__ __forceinline__ float iordu(uint_t y) {
  return (y & 0x80000000u) ? __uint_as_float(y & 0x7FFFFFFFu)
                           : __uint_as_float(~y);
}

// ---------------- K1: 1x1 conv reduce, c-split partials ----------------
// grid: 144 pixgroups(128 px) x 4 cq = 576, block 128. feat4 [cq][NROWS][64]
__global__ __launch_bounds__(128) void k_reduce(
    const float* __restrict__ x, const float* __restrict__ wr,
    float* __restrict__ feat4) {
  __shared__ float wl[64 * 64];  // 16 KB: [c_local][r]
  const int bi = blockIdx.x;
  const int pg = bi >> 2, cq = bi & 3;
  const int tid = threadIdx.x;
#pragma unroll
  for (int i = 0; i < 32; ++i) {
    const int idx = i * 128 + tid;
    const int c = idx >> 6, r = idx & 63;
    wl[c * 64 + r] = wr[(size_t)r * NC + cq * 64 + c];
  }
  __syncthreads();

  const int p = pg * 128 + tid;
  const int b = p >= NPIX;
  const int n = p - b * NPIX;
  const float* xp = x + (size_t)b * NC * NPIX + (size_t)cq * 64 * NPIX + n;

  float4 acc[16];
#pragma unroll
  for (int i = 0; i < 16; ++i) acc[i] = make_float4(0.f, 0.f, 0.f, 0.f);

  for (int c = 0; c < 64; ++c) {
    const float xv = xp[(size_t)c * NPIX];           // coalesced
    const float4* w4 = (const float4*)(wl + c * 64); // broadcast
#pragma unroll
    for (int i = 0; i < 16; ++i) {
      float4 w = w4[i];
      acc[i].x += w.x * xv; acc[i].y += w.y * xv;
      acc[i].z += w.z * xv; acc[i].w += w.w * xv;
    }
  }
  float4* o = (float4*)(feat4 + ((size_t)cq * NROWS + p) * 64);
#pragma unroll
  for (int i = 0; i < 16; ++i) o[i] = acc[i];  // 256B/lane contiguous
}

// ---------------- K1b: sum partials + normalize + bf16 hi ----------------
__global__ __launch_bounds__(256) void k_normsplit(
    const float* __restrict__ feat4, float* __restrict__ nf,
    ushort_t* __restrict__ hi) {
  const int t = blockIdx.x * 256 + threadIdx.x;
  const int p = t >> 2, q = t & 3;  // 4 lanes per pixel
  float4 v[4];
#pragma unroll
  for (int i = 0; i < 4; ++i) v[i] = make_float4(0.f, 0.f, 0.f, 0.f);
#pragma unroll
  for (int cq = 0; cq < 4; ++cq) {
    const float4* fp = (const float4*)(feat4 + ((size_t)cq * NROWS + p) * 64 + q * 16);
#pragma unroll
    for (int i = 0; i < 4; ++i) {
      float4 a = fp[i];
      v[i].x += a.x; v[i].y += a.y; v[i].z += a.z; v[i].w += a.w;
    }
  }
  float ssq = 0.f;
#pragma unroll
  for (int i = 0; i < 4; ++i)
    ssq += v[i].x * v[i].x + v[i].y * v[i].y + v[i].z * v[i].z + v[i].w * v[i].w;
  ssq += __shfl_xor(ssq, 1);
  ssq += __shfl_xor(ssq, 2);
  const float inv = 1.f / fmaxf(sqrtf(ssq), 1e-12f);

  float s[16];
#pragma unroll
  for (int i = 0; i < 4; ++i) {
    s[i * 4 + 0] = v[i].x * inv; s[i * 4 + 1] = v[i].y * inv;
    s[i * 4 + 2] = v[i].z * inv; s[i * 4 + 3] = v[i].w * inv;
  }
  float4* no = (float4*)(nf + (size_t)p * RC + q * 16);
#pragma unroll
  for (int i = 0; i < 4; ++i)
    no[i] = make_float4(s[i * 4], s[i * 4 + 1], s[i * 4 + 2], s[i * 4 + 3]);

  uint_t hs[16];
#pragma unroll
  for (int i = 0; i < 16; ++i) hs[i] = f2bf(s[i]);
  uint4* ho = (uint4*)(hi + (size_t)p * RC + q * 16);
#pragma unroll
  for (int h = 0; h < 2; ++h)
    ho[h] = make_uint4(hs[h*8+0] | (hs[h*8+1] << 16), hs[h*8+2] | (hs[h*8+3] << 16),
                       hs[h*8+4] | (hs[h*8+5] << 16), hs[h*8+6] | (hs[h*8+7] << 16));
}

// ---------------- K2: single sim pass — per-16-col-subtile maxima ----------------
// grid: 144 rowblocks(128 rows) x 9 col-splits = 1296. LDS staging (R4-proven),
// subtile maxima quantized u16, accumulated in per-wave LDS, dumped coalesced
// line-owned at kernel end (smax[row][576], row stride 1152B = 9 lines).
__global__ __launch_bounds__(256) void k_sim_max(
    const ushort_t* __restrict__ nf_hi, ushort_t* __restrict__ smax) {
  __shared__ ushort_t sh[CT * SST];       // 18432 B staging
  __shared__ ushort_t lacc[4][32][64];    // 16384 B per-wave subtile maxima
  const int rb = blockIdx.x / NQ, q = blockIdx.x % NQ;
  const int tid = threadIdx.x, wave = tid >> 6, lane = tid & 63;
  const int n = lane & 15, quad = lane >> 4;
  const int r0 = rb * 128 + wave * 32 + n, r1 = r0 + 16;
  const int b = rb >= 72;
  const size_t cbase = (size_t)b * NPIX;

  const bf16x8 bh00 = *(const bf16x8*)(nf_hi + (size_t)r0 * 64 + quad * 8);
  const bf16x8 bh01 = *(const bf16x8*)(nf_hi + (size_t)r0 * 64 + 32 + quad * 8);
  const bf16x8 bh10 = *(const bf16x8*)(nf_hi + (size_t)r1 * 64 + quad * 8);
  const bf16x8 bh11 = *(const bf16x8*)(nf_hi + (size_t)r1 * 64 + 32 + quad * 8);

  const int sc = tid >> 1, sseg = (tid & 1) * 32;

  for (int t = 0; t < NT2; ++t) {
    const int cb = q * QC + t * CT;
    __syncthreads();
    {
      const uint4* g = (const uint4*)(nf_hi + (cbase + cb + sc) * 64 + sseg);
      uint4* d = (uint4*)(sh + sc * SST + sseg);
#pragma unroll
      for (int i = 0; i < 4; ++i) d[i] = g[i];
    }
    __syncthreads();

#pragma unroll 2
    for (int st = 0; st < 8; ++st) {
      const ushort_t* ap = sh + (st * 16 + n) * SST + quad * 8;
      bf16x8 ah0 = *(const bf16x8*)ap;
      bf16x8 ah1 = *(const bf16x8*)(ap + 32);
      f32x4 z = {0.f, 0.f, 0.f, 0.f};
      f32x4 a0 = __builtin_amdgcn_mfma_f32_16x16x32_bf16(ah0, bh00, z, 0, 0, 0);
      a0 = __builtin_amdgcn_mfma_f32_16x16x32_bf16(ah1, bh01, a0, 0, 0, 0);
      f32x4 a1 = __builtin_amdgcn_mfma_f32_16x16x32_bf16(ah0, bh10, z, 0, 0, 0);
      a1 = __builtin_amdgcn_mfma_f32_16x16x32_bf16(ah1, bh11, a1, 0, 0, 0);
      float mx0 = fmaxf(fmaxf(a0[0], a0[1]), fmaxf(a0[2], a0[3]));
      float mx1 = fmaxf(fmaxf(a1[0], a1[1]), fmaxf(a1[2], a1[3]));
      // cross-quad: full 16-col subtile max for this lane's row
      mx0 = fmaxf(mx0, __shfl_xor(mx0, 16));
      mx0 = fmaxf(mx0, __shfl_xor(mx0, 32));
      mx1 = fmaxf(mx1, __shfl_xor(mx1, 16));
      mx1 = fmaxf(mx1, __shfl_xor(mx1, 32));
      if (quad == (st & 3)) {  // one quad stores both row-halves
        const int u = t * 8 + st;
        lacc[wave][n][u] = (ushort_t)(ordu(mx0) >> 16);
        lacc[wave][n + 16][u] = (ushort_t)(ordu(mx1) >> 16);
      }
    }
  }

  // dump: per (row, split) exactly 64 u16 = one 128B line, block-owned
  const int rowbase = rb * 128 + wave * 32;
  const int half = lane >> 5, cp = lane & 31;
#pragma unroll
  for (int r = 0; r < 16; ++r) {
    const int rl = half * 16 + r;
    const uint_t v = *(const uint_t*)&lacc[wave][rl][cp * 2];
    *(uint_t*)(smax + (size_t)(rowbase + rl) * NCHK + q * 64 + cp * 2) = v;
  }
}

// ---------------- K3: threshold + collect + exact fp32 score + top-16 + gather ----------------
// wave per row; grid NROWS/4 = 4608
__global__ __launch_bounds__(256) void k_merge_gather(
    const float* __restrict__ nf, const ushort_t* __restrict__ smax,
    float* __restrict__ corr) {
  __shared__ ushort_t cand[4][MAXS];
  const int wave = threadIdx.x >> 6, lane = threadIdx.x & 63;
  const int row = blockIdx.x * 4 + wave;
  const int b = row >= NPIX;
  const float* nfb = nf + (size_t)b * NPIX * RC;

  float4 rv[16];
  const float4* r4 = (const float4*)(nf + (size_t)row * RC);
#pragma unroll
  for (int i = 0; i < 16; ++i) rv[i] = r4[i];  // wave-uniform broadcast

  // row's 576 subtile maxima, coalesced 128B reads
  uint_t h[9], ho[9];
#pragma unroll
  for (int i = 0; i < 9; ++i) {
    h[i] = (uint_t)smax[(size_t)row * NCHK + i * 64 + lane];
    ho[i] = h[i];
  }

  // wave top-16 of 576 (u16 domain, monotone); duplicates-clearing only lowers
  // m16 => threshold only gets safer
  uint_t m16 = 0;
#pragma unroll
  for (int k = 0; k < TK; ++k) {
    uint_t lm = h[0];
#pragma unroll
    for (int j = 1; j < 9; ++j) lm = lm > h[j] ? lm : h[j];
#pragma unroll
    for (int d = 1; d < 64; d <<= 1) {
      uint_t o = __shfl_xor(lm, d);
      lm = o > lm ? o : lm;
    }
    m16 = lm;
#pragma unroll
    for (int j = 0; j < 9; ++j) if (h[j] == lm) h[j] = 0;
  }
  const float d16 = iordu(m16 << 16);
  const uint_t hT = ordu(d16 - MARGIN) >> 16;

  // ballot-compact candidate subtiles into per-wave LDS
  int cnt = 0;
  const unsigned long long ltm = (1ull << lane) - 1ull;
#pragma unroll
  for (int i = 0; i < 9; ++i) {
    const bool p = ho[i] >= hT;
    const unsigned long long mk = __ballot(p);
    if (p) {
      const int off = cnt + (int)__popcll(mk & ltm);
      if (off < MAXS) cand[wave][off] = (ushort_t)(i * 64 + lane);
    }
    cnt += (int)__popcll(mk);
  }
  if (cnt > MAXS) cnt = MAXS;

  // exact fp32 dots: lane scores col (lane&15) of subtile g*4+(lane>>4)
  unsigned long long kk[MAXG];
  const int myq = lane >> 4, myn = lane & 15;
#pragma unroll
  for (int g = 0; g < MAXG; ++g) {
    kk[g] = 0;
    const int si = g * 4 + myq;
    if (si < cnt) {
      const int col = (int)cand[wave][si] * 16 + myn;
      const float4* gp = (const float4*)(nfb + (size_t)col * RC);
      float s = 0.f;
#pragma unroll
      for (int i = 0; i < 16; ++i) {
        float4 a = gp[i];
        s += a.x * rv[i].x + a.y * rv[i].y + a.z * rv[i].z + a.w * rv[i].w;
      }
      kk[g] = ((unsigned long long)ordu(s) << 32) | (uint_t)(~(uint_t)col);
    }
  }

  // exact top-16 by (value, -index); >=256 valid keys guaranteed
  int sel[TK];
#pragma unroll
  for (int t = 0; t < TK; ++t) {
    unsigned long long mm = kk[0];
#pragma unroll
    for (int g = 1; g < MAXG; ++g) mm = kk[g] > mm ? kk[g] : mm;
#pragma unroll
    for (int d = 1; d < 64; d <<= 1) {
      unsigned long long o = __shfl_xor(mm, d);
      mm = o > mm ? o : mm;
    }
    sel[t] = (int)(~(uint_t)(mm & 0xFFFFFFFFull));
#pragma unroll
    for (int g = 0; g < MAXG; ++g) if (kk[g] == mm) kk[g] = 0;
  }

  float acc = 0.f;
#pragma unroll
  for (int t = 0; t < TK; ++t)
    acc += nfb[(size_t)sel[t] * RC + lane];  // coalesced 256B per t
  corr[(size_t)row * RC + lane] = acc * 0.0625f;
}

// ---------------- K4: proj back to C channels + residual add ----------------
// grid: 72 pixgroups x 8 channel-eighths = 576
__global__ __launch_bounds__(256) void k_proj_add(
    const float* __restrict__ x, const float* __restrict__ wp,
    const float* __restrict__ corr, float* __restrict__ out) {
  const int pg = blockIdx.x >> 3, cq = blockIdx.x & 7;
  const int tid = threadIdx.x;

  __shared__ float wl[32 * RC];  // 8 KB
  {
    const float4* src = (const float4*)(wp + (size_t)cq * 32 * RC);
    float4* dst = (float4*)wl;
#pragma unroll
    for (int i = 0; i < 2; ++i) dst[i * 256 + tid] = src[i * 256 + tid];
  }

  const int p = pg * 256 + tid;
  const int b = p >= NPIX;
  const int n = p - b * NPIX;

  float4 cr[16];
  const float4* c4 = (const float4*)(corr + (size_t)p * RC);
#pragma unroll
  for (int i = 0; i < 16; ++i) cr[i] = c4[i];
  __syncthreads();

  const size_t xb = (size_t)b * NC * NPIX + n;
  for (int cl = 0; cl < 32; ++cl) {
    const float4* w4 = (const float4*)(wl + cl * RC);  // broadcast
    float s = 0.f;
#pragma unroll
    for (int i = 0; i < 16; ++i) {
      float4 w = w4[i];
      s += w.x * cr[i].x + w.y * cr[i].y + w.z * cr[i].z + w.w * cr[i].w;
    }
    const int c = cq * 32 + cl;
    const size_t oi = xb + (size_t)c * NPIX;
    out[oi] = x[oi] + s;  // coalesced
  }
}

extern "C" void kernel_launch(void* const* d_in, const int* in_sizes, int n_in,
                              void* d_out, int out_size, void* d_ws, size_t ws_size,
                              hipStream_t stream) {
  const float* x = (const float*)d_in[0];
  const float* wr = (const float*)d_in[1];
  const float* wp = (const float*)d_in[2];
  float* out = (float*)d_out;

  char* ws = (char*)d_ws;
  // region1 (21,233,664 B) time-shares feat4 (18.9 MB, reduce->normsplit)
  // and smax (21.2 MB, sim_max->merge) — lifetimes disjoint.
  float* feat4 = (float*)ws;
  ushort_t* smax = (ushort_t*)ws;
  float* corr = (float*)(ws + 21233664);
  float* nf = (float*)(ws + 25952256);
  ushort_t* nf_hi = (ushort_t*)(ws + 30670848);
  // total 33,030,144 B

  hipLaunchKernelGGL(k_reduce, dim3(576), dim3(128), 0, stream, x, wr, feat4);
  hipLaunchKernelGGL(k_normsplit, dim3(288), dim3(256), 0, stream, feat4, nf, nf_hi);
  hipLaunchKernelGGL(k_sim_max, dim3(144 * NQ), dim3(256), 0, stream, nf_hi, smax);
  hipLaunchKernelGGL(k_merge_gather, dim3(NROWS / 4), dim3(256), 0, stream,
                     nf, smax, corr);
  hipLaunchKernelGGL(k_proj_add, dim3(576), dim3(256), 0, stream, x, wp, corr, out);
}

// Round 8
// 323.114 us; speedup vs baseline: 2.1144x; 2.1144x over previous
//
#include <hip/hip_runtime.h>
#include <cstdint>
#include <cstddef>

#define NPIX 9216          // 96*96
#define NB 2
#define NC 256
#define RC 64
#define TK 16
#define NROWS (NB * NPIX)  // 18432
#define NSP 24             // col splits
#define CPS 384            // cols per split
#define NSUB 24            // 16-col subtiles per split
#define SST 72             // LDS col stride in ushorts (2-way reads = free)
#define CAP 4              // candidate slots per (row,split,quad) stream
#define MARGIN 0.008f      // 2*e, e <= (2*2^-9 + 2^-18) * ||a||*||b||

typedef unsigned short ushort_t;
typedef unsigned char uchar_t;
typedef unsigned int uint_t;
typedef unsigned long long u64;
typedef __bf16 bf16x8 __attribute__((ext_vector_type(8)));
typedef float f32x4 __attribute__((ext_vector_type(4)));

__device__ __forceinline__ uint_t f2bf(float x) {
  uint_t u = __float_as_uint(x);
  return (u + 0x7FFFu + ((u >> 16) & 1u)) >> 16;
}
__device__ __forceinline__ uint_t ordu(float v) {
  uint_t u = __float_as_uint(v);
  return (u & 0x80000000u) ? ~u : (u | 0x80000000u);
}

// ---------------- K1: 1x1 conv reduce, c-split partials ----------------
__global__ __launch_bounds__(128) void k_reduce(
    const float* __restrict__ x, const float* __restrict__ wr,
    float* __restrict__ feat4) {
  __shared__ float wl[64 * 64];
  const int bi = blockIdx.x;
  const int pg = bi >> 2, cq = bi & 3;
  const int tid = threadIdx.x;
#pragma unroll
  for (int i = 0; i < 32; ++i) {
    const int idx = i * 128 + tid;
    const int c = idx >> 6, r = idx & 63;
    wl[c * 64 + r] = wr[(size_t)r * NC + cq * 64 + c];
  }
  __syncthreads();

  const int p = pg * 128 + tid;
  const int b = p >= NPIX;
  const int n = p - b * NPIX;
  const float* xp = x + (size_t)b * NC * NPIX + (size_t)cq * 64 * NPIX + n;

  float4 acc[16];
#pragma unroll
  for (int i = 0; i < 16; ++i) acc[i] = make_float4(0.f, 0.f, 0.f, 0.f);
  for (int c = 0; c < 64; ++c) {
    const float xv = xp[(size_t)c * NPIX];
    const float4* w4 = (const float4*)(wl + c * 64);
#pragma unroll
    for (int i = 0; i < 16; ++i) {
      float4 w = w4[i];
      acc[i].x += w.x * xv; acc[i].y += w.y * xv;
      acc[i].z += w.z * xv; acc[i].w += w.w * xv;
    }
  }
  float4* o = (float4*)(feat4 + ((size_t)cq * NROWS + p) * 64);
#pragma unroll
  for (int i = 0; i < 16; ++i) o[i] = acc[i];
}

// ---------------- K1b: sum partials + normalize + bf16 hi ----------------
__global__ __launch_bounds__(256) void k_normsplit(
    const float* __restrict__ feat4, float* __restrict__ nf,
    ushort_t* __restrict__ hi) {
  const int t = blockIdx.x * 256 + threadIdx.x;
  const int p = t >> 2, q = t & 3;
  float4 v[4];
#pragma unroll
  for (int i = 0; i < 4; ++i) v[i] = make_float4(0.f, 0.f, 0.f, 0.f);
#pragma unroll
  for (int cq = 0; cq < 4; ++cq) {
    const float4* fp = (const float4*)(feat4 + ((size_t)cq * NROWS + p) * 64 + q * 16);
#pragma unroll
    for (int i = 0; i < 4; ++i) {
      float4 a = fp[i];
      v[i].x += a.x; v[i].y += a.y; v[i].z += a.z; v[i].w += a.w;
    }
  }
  float ssq = 0.f;
#pragma unroll
  for (int i = 0; i < 4; ++i)
    ssq += v[i].x * v[i].x + v[i].y * v[i].y + v[i].z * v[i].z + v[i].w * v[i].w;
  ssq += __shfl_xor(ssq, 1);
  ssq += __shfl_xor(ssq, 2);
  const float inv = 1.f / fmaxf(sqrtf(ssq), 1e-12f);

  float s[16];
#pragma unroll
  for (int i = 0; i < 4; ++i) {
    s[i * 4 + 0] = v[i].x * inv; s[i * 4 + 1] = v[i].y * inv;
    s[i * 4 + 2] = v[i].z * inv; s[i * 4 + 3] = v[i].w * inv;
  }
  float4* no = (float4*)(nf + (size_t)p * RC + q * 16);
#pragma unroll
  for (int i = 0; i < 4; ++i)
    no[i] = make_float4(s[i * 4], s[i * 4 + 1], s[i * 4 + 2], s[i * 4 + 3]);

  uint_t hs[16];
#pragma unroll
  for (int i = 0; i < 16; ++i) hs[i] = f2bf(s[i]);
  uint4* ho = (uint4*)(hi + (size_t)p * RC + q * 16);
#pragma unroll
  for (int h = 0; h < 2; ++h)
    ho[h] = make_uint4(hs[h*8+0] | (hs[h*8+1] << 16), hs[h*8+2] | (hs[h*8+3] << 16),
                       hs[h*8+4] | (hs[h*8+5] << 16), hs[h*8+6] | (hs[h*8+7] << 16));
}

// ---------------- K2a: pass A — stage-once, barrier-free K-loop, chunk maxima ----------------
// grid: 72 rowblocks(256 rows) x 24 splits = 1728. Wave owns 64 rows (4 rowgroups).
__global__ __launch_bounds__(256) void k_sim_max(
    const ushort_t* __restrict__ nf_hi, float* __restrict__ tmax) {
  __shared__ ushort_t sh[CPS * SST];  // 55296 B
  const int rb = blockIdx.x / NSP, s = blockIdx.x % NSP;
  const int tid = threadIdx.x, wave = tid >> 6, lane = tid & 63;
  const int n = lane & 15, q = lane >> 4;
  const int rbase = rb * 256 + wave * 64;
  const int b = rb >= 36;
  const size_t cbase = (size_t)b * NPIX;
  const int col0 = s * CPS;

  bf16x8 bh[4][2];
#pragma unroll
  for (int g = 0; g < 4; ++g) {
    const ushort_t* bp = nf_hi + (size_t)(rbase + 16 * g + n) * 64 + q * 8;
    bh[g][0] = *(const bf16x8*)bp;
    bh[g][1] = *(const bf16x8*)(bp + 32);
  }

  {  // stage 384 cols = 3072 uint4, fully coalesced; conflict-free LDS writes
    const uint4* gsrc = (const uint4*)(nf_hi + (cbase + col0) * 64);
#pragma unroll
    for (int i = 0; i < 12; ++i) {
      const int idx = i * 256 + tid;
      *(uint4*)(sh + (idx >> 3) * SST + (idx & 7) * 8) = gsrc[idx];
    }
  }
  __syncthreads();  // the only compute barrier

  float cm[4] = {-1e30f, -1e30f, -1e30f, -1e30f};
#pragma unroll 2
  for (int u = 0; u < NSUB; ++u) {
    const ushort_t* ap = sh + (u * 16 + n) * SST + q * 8;
    bf16x8 ah0 = *(const bf16x8*)ap;
    bf16x8 ah1 = *(const bf16x8*)(ap + 32);
#pragma unroll
    for (int g = 0; g < 4; ++g) {
      f32x4 z = {0.f, 0.f, 0.f, 0.f};
      f32x4 a = __builtin_amdgcn_mfma_f32_16x16x32_bf16(ah0, bh[g][0], z, 0, 0, 0);
      a = __builtin_amdgcn_mfma_f32_16x16x32_bf16(ah1, bh[g][1], a, 0, 0, 0);
      cm[g] = fmaxf(cm[g], fmaxf(fmaxf(a[0], a[1]), fmaxf(a[2], a[3])));
    }
  }

  // route chunk maxima through LDS, dump one coalesced 4KB block
  __syncthreads();
  float* shf = (float*)sh;
#pragma unroll
  for (int g = 0; g < 4; ++g)
    shf[(wave * 64 + 16 * g + n) * 4 + q] = cm[g];
  __syncthreads();
  float4* dst = (float4*)(tmax + ((size_t)s * NROWS + rb * 256) * 4);
  dst[tid] = ((const float4*)shf)[tid];
}

// ---------------- K2b: threshold = 16th largest of 96 chunk maxima - margin ----------------
__global__ __launch_bounds__(256) void k_thresh(
    const float* __restrict__ tmax, float* __restrict__ Tb) {
  const int wave = threadIdx.x >> 6, lane = threadIdx.x & 63;
  const int row = blockIdx.x * 4 + wave;
  float v0 = tmax[((size_t)(lane >> 2) * NROWS + row) * 4 + (lane & 3)];
  float v1 = (lane < 32)
      ? tmax[((size_t)(16 + (lane >> 2)) * NROWS + row) * 4 + (lane & 3)]
      : -1e30f;
  float m = -1e30f;
#pragma unroll
  for (int k = 0; k < TK; ++k) {
    float c = fmaxf(v0, v1);
#pragma unroll
    for (int d = 1; d < 64; d <<= 1) c = fmaxf(c, __shfl_xor(c, d));
    m = c;
    if (v0 == m) v0 = -1e30f;  // dup-clearing only lowers T: safe
    if (v1 == m) v1 = -1e30f;
  }
  if (lane == 0) Tb[row] = m - MARGIN;
}

// ---------------- K2c: pass B — same loop, collect cols >= T into packed u64 slots ----------------
__global__ __launch_bounds__(256) void k_collect(
    const ushort_t* __restrict__ nf_hi, const float* __restrict__ Tb,
    u64* __restrict__ cidx, uchar_t* __restrict__ ccnt) {
  __shared__ ushort_t sh[CPS * SST];
  const int rb = blockIdx.x / NSP, s = blockIdx.x % NSP;
  const int tid = threadIdx.x, wave = tid >> 6, lane = tid & 63;
  const int n = lane & 15, q = lane >> 4;
  const int rbase = rb * 256 + wave * 64;
  const int b = rb >= 36;
  const size_t cbase = (size_t)b * NPIX;
  const int col0 = s * CPS;

  bf16x8 bh[4][2];
  float Tg[4];
#pragma unroll
  for (int g = 0; g < 4; ++g) {
    const ushort_t* bp = nf_hi + (size_t)(rbase + 16 * g + n) * 64 + q * 8;
    bh[g][0] = *(const bf16x8*)bp;
    bh[g][1] = *(const bf16x8*)(bp + 32);
    Tg[g] = Tb[rbase + 16 * g + n];
  }

  {
    const uint4* gsrc = (const uint4*)(nf_hi + (cbase + col0) * 64);
#pragma unroll
    for (int i = 0; i < 12; ++i) {
      const int idx = i * 256 + tid;
      *(uint4*)(sh + (idx >> 3) * SST + (idx & 7) * 8) = gsrc[idx];
    }
  }
  __syncthreads();

  u64 pk[4] = {0, 0, 0, 0};
  int cnt[4] = {0, 0, 0, 0};
#pragma unroll 2
  for (int u = 0; u < NSUB; ++u) {
    const ushort_t* ap = sh + (u * 16 + n) * SST + q * 8;
    bf16x8 ah0 = *(const bf16x8*)ap;
    bf16x8 ah1 = *(const bf16x8*)(ap + 32);
    const int colb = col0 + u * 16 + q * 4;
#pragma unroll
    for (int g = 0; g < 4; ++g) {
      f32x4 z = {0.f, 0.f, 0.f, 0.f};
      f32x4 a = __builtin_amdgcn_mfma_f32_16x16x32_bf16(ah0, bh[g][0], z, 0, 0, 0);
      a = __builtin_amdgcn_mfma_f32_16x16x32_bf16(ah1, bh[g][1], a, 0, 0, 0);
      const float mx = fmaxf(fmaxf(a[0], a[1]), fmaxf(a[2], a[3]));
      if (mx >= Tg[g]) {
#pragma unroll
        for (int r = 0; r < 4; ++r) {
          const bool take = (a[r] >= Tg[g]);
          if (take && cnt[g] < CAP)
            pk[g] |= ((u64)(uint_t)(colb + r)) << (cnt[g] * 16);
          cnt[g] += take ? 1 : 0;
        }
      }
    }
  }

  // dump via LDS: 8KB pk + 1KB cnt, coalesced
  __syncthreads();
  u64* shp = (u64*)sh;
  uchar_t* shc = (uchar_t*)sh + 8192;
#pragma unroll
  for (int g = 0; g < 4; ++g) {
    const int rlq = (wave * 64 + 16 * g + n) * 4 + q;
    shp[rlq] = pk[g];
    shc[rlq] = (uchar_t)min(cnt[g], CAP);
  }
  __syncthreads();
  u64* gp = cidx + ((size_t)s * NROWS + rb * 256) * 4;
#pragma unroll
  for (int k = 0; k < 4; ++k) gp[k * 256 + tid] = shp[k * 256 + tid];
  ((uint_t*)(ccnt + ((size_t)s * NROWS + rb * 256) * 4))[tid] =
      ((const uint_t*)shc)[tid];
}

// ---------------- K3: exact fp32 re-score + top-16 + gather + mean ----------------
// wave per row, lane per stream (96 streams: lane l -> st l, and l<32 -> st 64+l)
__global__ __launch_bounds__(256) void k_merge_gather(
    const float* __restrict__ nf, const u64* __restrict__ cidx,
    const uchar_t* __restrict__ ccnt, float* __restrict__ corr) {
  const int wave = threadIdx.x >> 6, lane = threadIdx.x & 63;
  const int row = blockIdx.x * 4 + wave;
  const int b = row >= NPIX;
  const int rl = row - b * NPIX;
  const float* nfb = nf + (size_t)b * NPIX * RC;

  float4 rv[16];
  const float4* r4 = (const float4*)(nf + (size_t)row * RC);
#pragma unroll
  for (int i = 0; i < 16; ++i) rv[i] = r4[i];  // wave-uniform broadcast

  const size_t iA = ((size_t)(lane >> 2) * NROWS + row) * 4 + (lane & 3);
  const u64 pkA = cidx[iA];
  int cnA = (int)ccnt[iA];
  u64 pkB = 0;
  int cnB = 0;
  if (lane < 32) {
    const size_t iB = ((size_t)(16 + (lane >> 2)) * NROWS + row) * 4 + (lane & 3);
    pkB = cidx[iB];
    cnB = (int)ccnt[iB];
  }

  u64 kk[8];
#pragma unroll
  for (int j = 0; j < 8; ++j) kk[j] = 0;
#pragma unroll
  for (int j = 0; j < 4; ++j) {
    if (j < cnA) {
      const int c = (int)((pkA >> (j * 16)) & 0xFFFFull);
      const float4* gp = (const float4*)(nfb + (size_t)c * RC);
      float sv = 0.f;
#pragma unroll
      for (int i = 0; i < 16; ++i) {
        float4 a = gp[i];
        sv += a.x * rv[i].x + a.y * rv[i].y + a.z * rv[i].z + a.w * rv[i].w;
      }
      kk[j] = ((u64)ordu(sv) << 32) | (uint_t)(~(uint_t)c);
    }
  }
#pragma unroll
  for (int j = 0; j < 4; ++j) {
    if (j < cnB) {
      const int c = (int)((pkB >> (j * 16)) & 0xFFFFull);
      const float4* gp = (const float4*)(nfb + (size_t)c * RC);
      float sv = 0.f;
#pragma unroll
      for (int i = 0; i < 16; ++i) {
        float4 a = gp[i];
        sv += a.x * rv[i].x + a.y * rv[i].y + a.z * rv[i].z + a.w * rv[i].w;
      }
      kk[4 + j] = ((u64)ordu(sv) << 32) | (uint_t)(~(uint_t)c);
    }
  }

  int sel[TK];
#pragma unroll
  for (int t = 0; t < TK; ++t) {
    u64 mm = kk[0];
#pragma unroll
    for (int j = 1; j < 8; ++j) mm = kk[j] > mm ? kk[j] : mm;
#pragma unroll
    for (int d = 1; d < 64; d <<= 1) {
      u64 o = __shfl_xor(mm, d);
      mm = (o > mm) ? o : mm;
    }
    sel[t] = (mm == 0) ? rl : (int)(~(uint_t)(mm & 0xFFFFFFFFull));
#pragma unroll
    for (int j = 0; j < 8; ++j)
      if (kk[j] == mm) kk[j] = 0;
  }

  float acc = 0.f;
#pragma unroll
  for (int t = 0; t < TK; ++t)
    acc += nfb[(size_t)sel[t] * RC + lane];  // coalesced 256B per t
  corr[(size_t)row * RC + lane] = acc * 0.0625f;
}

// ---------------- K4: proj back to C channels + residual add ----------------
__global__ __launch_bounds__(256) void k_proj_add(
    const float* __restrict__ x, const float* __restrict__ wp,
    const float* __restrict__ corr, float* __restrict__ out) {
  const int pg = blockIdx.x >> 3, cq = blockIdx.x & 7;
  const int tid = threadIdx.x;

  __shared__ float wl[32 * RC];
  {
    const float4* src = (const float4*)(wp + (size_t)cq * 32 * RC);
    float4* dst = (float4*)wl;
#pragma unroll
    for (int i = 0; i < 2; ++i) dst[i * 256 + tid] = src[i * 256 + tid];
  }

  const int p = pg * 256 + tid;
  const int b = p >= NPIX;
  const int n = p - b * NPIX;

  float4 cr[16];
  const float4* c4 = (const float4*)(corr + (size_t)p * RC);
#pragma unroll
  for (int i = 0; i < 16; ++i) cr[i] = c4[i];
  __syncthreads();

  const size_t xb = (size_t)b * NC * NPIX + n;
  for (int cl = 0; cl < 32; ++cl) {
    const float4* w4 = (const float4*)(wl + cl * RC);
    float s = 0.f;
#pragma unroll
    for (int i = 0; i < 16; ++i) {
      float4 w = w4[i];
      s += w.x * cr[i].x + w.y * cr[i].y + w.z * cr[i].z + w.w * cr[i].w;
    }
    const int c = cq * 32 + cl;
    const size_t oi = xb + (size_t)c * NPIX;
    out[oi] = x[oi] + s;
  }
}

extern "C" void kernel_launch(void* const* d_in, const int* in_sizes, int n_in,
                              void* d_out, int out_size, void* d_ws, size_t ws_size,
                              hipStream_t stream) {
  const float* x = (const float*)d_in[0];
  const float* wr = (const float*)d_in[1];
  const float* wp = (const float*)d_in[2];
  float* out = (float*)d_out;

  char* ws = (char*)d_ws;
  // region A (23,003,136 B) time-shares feat4 (18.9 MB, reduce->normsplit) with
  // tmax/ccnt/cidx (sim passes -> merge) — lifetimes disjoint.
  float* feat4 = (float*)ws;
  float* tmax = (float*)ws;                        // 7,077,888
  uchar_t* ccnt = (uchar_t*)(ws + 7077888);        // 1,769,472
  u64* cidx = (u64*)(ws + 8847360);                // 14,155,776 -> 23,003,136
  float* nf = (float*)(ws + 23003136);             // 4,718,592
  ushort_t* nf_hi = (ushort_t*)(ws + 27721728);    // 2,359,296
  float* Tb = (float*)(ws + 30081024);             // 73,728
  float* corr = (float*)(ws + 30154752);           // 4,718,592 -> 34,873,344 total

  hipLaunchKernelGGL(k_reduce, dim3(576), dim3(128), 0, stream, x, wr, feat4);
  hipLaunchKernelGGL(k_normsplit, dim3(288), dim3(256), 0, stream, feat4, nf, nf_hi);
  hipLaunchKernelGGL(k_sim_max, dim3(72 * NSP), dim3(256), 0, stream, nf_hi, tmax);
  hipLaunchKernelGGL(k_thresh, dim3(NROWS / 4), dim3(256), 0, stream, tmax, Tb);
  hipLaunchKernelGGL(k_collect, dim3(72 * NSP), dim3(256), 0, stream,
                     nf_hi, Tb, cidx, ccnt);
  hipLaunchKernelGGL(k_merge_gather, dim3(NROWS / 4), dim3(256), 0, stream,
                     nf, cidx, ccnt, corr);
  hipLaunchKernelGGL(k_proj_add, dim3(576), dim3(256), 0, stream, x, wp, corr, out);
}